// Round 7
// baseline (339.461 us; speedup 1.0000x reference)
//
#include <hip/hip_runtime.h>
#include <hip/hip_bf16.h>

typedef __attribute__((ext_vector_type(8))) short bh8;
typedef __attribute__((ext_vector_type(4))) float f32x4;

__device__ __forceinline__ float bfbits2f(unsigned short s) {
    union { unsigned int u; float f; } cv;
    cv.u = ((unsigned int)s) << 16;
    return cv.f;
}
__device__ __forceinline__ unsigned short f2bfbits(float f) {
    union { float f; unsigned int u; } cv; cv.f = f;
    unsigned int u = cv.u;
    u += 0x7fffu + ((u >> 16) & 1u);   // round-to-nearest-even
    return (unsigned short)(u >> 16);
}
__device__ __forceinline__ unsigned int pack2bf(float a, float b) {
    return (unsigned int)f2bfbits(a) | (((unsigned int)f2bfbits(b)) << 16);
}
// unpack 8 bf16 from a uint4 into floats
__device__ __forceinline__ void unpack8(const uint4& u, float* f) {
    unsigned int uu[4] = {u.x, u.y, u.z, u.w};
    #pragma unroll
    for (int i = 0; i < 4; i++) {
        f[2 * i]     = bfbits2f((unsigned short)(uu[i] & 0xffffu));
        f[2 * i + 1] = bfbits2f((unsigned short)(uu[i] >> 16));
    }
}

// load 8 consecutive fp32, convert to a bf16x8 MFMA fragment
__device__ __forceinline__ bh8 load_frag_f32(const float* __restrict__ p) {
    float4 f0 = *reinterpret_cast<const float4*>(p);
    float4 f1 = *reinterpret_cast<const float4*>(p + 4);
    bh8 r;
    r[0] = (short)f2bfbits(f0.x); r[1] = (short)f2bfbits(f0.y);
    r[2] = (short)f2bfbits(f0.z); r[3] = (short)f2bfbits(f0.w);
    r[4] = (short)f2bfbits(f1.x); r[5] = (short)f2bfbits(f1.y);
    r[6] = (short)f2bfbits(f1.z); r[7] = (short)f2bfbits(f1.w);
    return r;
}

// ---------- W conv (64 blocks) + histogram-with-rank (rest): blockIdx split ----------
__global__ __launch_bounds__(256)
void wconv_hist(const float* __restrict__ w0, const float* __restrict__ w1,
                const float* __restrict__ w2, const float* __restrict__ w3,
                unsigned short* __restrict__ o0, unsigned short* __restrict__ o1,
                unsigned short* __restrict__ o2, unsigned short* __restrict__ o3,
                const int* __restrict__ ei, int* __restrict__ counts,
                int* __restrict__ rank, int E)
{
    if (blockIdx.x < 64) {
        const float* src[4] = {w0, w1, w2, w3};
        unsigned short* dst[4] = {o0, o1, o2, o3};
        const float* s = src[blockIdx.x >> 4];
        unsigned short* d = dst[blockIdx.x >> 4];
        int i = ((blockIdx.x & 15) * 256 + threadIdx.x) * 4;
        float4 f = *reinterpret_cast<const float4*>(&s[i]);
        uint2 p;
        p.x = pack2bf(f.x, f.y);
        p.y = pack2bf(f.z, f.w);
        *reinterpret_cast<uint2*>(&d[i]) = p;
        return;
    }
    int e = (blockIdx.x - 64) * 256 + threadIdx.x;
    if (e < E) {
        int2 rc = reinterpret_cast<const int2*>(ei)[e];
        rank[e] = atomicAdd(&counts[rc.y], 1);
    }
}

// ---------- scans ----------
__device__ __forceinline__ int wave_incl_scan(int v, int lane) {
    #pragma unroll
    for (int off = 1; off < 64; off <<= 1) {
        int y = __shfl_up(v, off);
        if (lane >= off) v += y;
    }
    return v;
}

__global__ __launch_bounds__(1024)
void scan1_kernel(const int* __restrict__ counts, int* __restrict__ offs,
                  int* __restrict__ blkSum, int n)
{
    __shared__ int wsum[16];
    __shared__ int woff[16];
    const int t = threadIdx.x, lane = t & 63, w = t >> 6;
    int i = blockIdx.x * 1024 + t;
    int x = (i < n) ? counts[i] : 0;
    int v = wave_incl_scan(x, lane);
    if (lane == 63) wsum[w] = v;
    __syncthreads();
    if (t == 0) {
        int s = 0;
        #pragma unroll
        for (int j = 0; j < 16; j++) { int tmp = wsum[j]; woff[j] = s; s += tmp; }
        blkSum[blockIdx.x] = s;
    }
    __syncthreads();
    if (i < n) offs[i] = woff[w] + v - x;
}

__global__ void scan2_kernel(const int* __restrict__ blkSum, int* __restrict__ blkOff,
                             int* __restrict__ offs, int nb, int n)
{
    const int lane = threadIdx.x;   // 64 threads
    int carry = 0;
    for (int base = 0; base < nb; base += 64) {
        int x = (base + lane < nb) ? blkSum[base + lane] : 0;
        int v = wave_incl_scan(x, lane);
        if (base + lane < nb) blkOff[base + lane] = carry + v - x;
        carry += __shfl(v, 63);
    }
    if (lane == 0) offs[n] = carry;
}

__global__ __launch_bounds__(1024)
void scan3_kernel(int* __restrict__ offs, const int* __restrict__ blkOff, int n)
{
    int i = blockIdx.x * 1024 + threadIdx.x;
    if (i < n) offs[i] += blkOff[blockIdx.x];
}

// ---------- fused QKV GEMM + atomic-free scatter (blockIdx split) ----------
__global__ __launch_bounds__(256)
void qkv_scatter(const float* __restrict__ A,
                 const unsigned short* __restrict__ Wqb, const float* __restrict__ bq,
                 const unsigned short* __restrict__ Wkb, const float* __restrict__ bk,
                 const unsigned short* __restrict__ Wvb, const float* __restrict__ bv,
                 unsigned short* __restrict__ Oq, unsigned short* __restrict__ Ok,
                 unsigned short* __restrict__ Ov, int M, int gx,
                 const int* __restrict__ ei, const int* __restrict__ offsets,
                 const int* __restrict__ rank, int* __restrict__ sorted_r,
                 int E, int nsb)
{
    if (blockIdx.x >= (unsigned)gx) {
        int sb = blockIdx.x - gx;
        int stride = nsb * 256;
        for (int e = sb * 256 + threadIdx.x; e < E; e += stride) {
            int2 rc = reinterpret_cast<const int2*>(ei)[e];
            sorted_r[offsets[rc.y] + rank[e]] = rc.x;
        }
        return;
    }

    const int lane = threadIdx.x & 63;
    const int w    = threadIdx.x >> 6;
    const int r0   = blockIdx.x * 128 + w * 32;
    const int lr   = lane & 15;
    const int lk   = (lane >> 4) * 8;
    const int cq   = (lane >> 4) * 4;

    bh8 a[2][4];
    #pragma unroll
    for (int jt = 0; jt < 2; jt++) {
        int row = r0 + jt * 16 + lr; if (row >= M) row = M - 1;
        const float* ap = &A[(size_t)row * 128 + lk];
        #pragma unroll
        for (int ks = 0; ks < 4; ks++) a[jt][ks] = load_frag_f32(ap + ks * 32);
    }

    const unsigned short* Ws[3] = {Wqb, Wkb, Wvb};
    const float* Bs[3] = {bq, bk, bv};
    unsigned short* Os[3] = {Oq, Ok, Ov};

    #pragma unroll
    for (int wsel = 0; wsel < 3; wsel++) {
        const unsigned short* W = Ws[wsel];
        f32x4 acc[2][8];
        #pragma unroll
        for (int jt = 0; jt < 2; jt++)
            #pragma unroll
            for (int it = 0; it < 8; it++)
                #pragma unroll
                for (int q = 0; q < 4; q++) acc[jt][it][q] = 0.f;

        #pragma unroll
        for (int ks = 0; ks < 4; ks++) {
            bh8 b[8];
            #pragma unroll
            for (int it = 0; it < 8; it++)
                b[it] = *reinterpret_cast<const bh8*>(
                    &W[(size_t)(it * 16 + lr) * 128 + ks * 32 + lk]);
            #pragma unroll
            for (int jt = 0; jt < 2; jt++)
                #pragma unroll
                for (int it = 0; it < 8; it++)
                    acc[jt][it] = __builtin_amdgcn_mfma_f32_16x16x32_bf16(
                        b[it], a[jt][ks], acc[jt][it], 0, 0, 0);
        }

        const float* bias = Bs[wsel];
        unsigned short* O = Os[wsel];
        #pragma unroll
        for (int jt = 0; jt < 2; jt++) {
            int row = r0 + jt * 16 + lr;
            if (row >= M) continue;
            #pragma unroll
            for (int it = 0; it < 8; it++) {
                float4 b4 = *reinterpret_cast<const float4*>(&bias[it * 16 + cq]);
                uint2 pk;
                pk.x = pack2bf(acc[jt][it][0] + b4.x, acc[jt][it][1] + b4.y);
                pk.y = pack2bf(acc[jt][it][2] + b4.z, acc[jt][it][3] + b4.w);
                *reinterpret_cast<uint2*>(&O[(size_t)row * 128 + it * 16 + cq]) = pk;
            }
        }
    }
}

// ---------- edge attention: one wave per node, 16-edge chunks, head-pair lanes ----------
// lane = (s = lane>>2 edge slot, sub = lane&3 head-pair). Each lane computes FULL
// scores for heads 2sub, 2sub+1 of edge s (no cross-lane score reduce).
__global__ __launch_bounds__(256)
void edge_attn_kernel(const unsigned short* __restrict__ qb,
                      const unsigned short* __restrict__ kb,
                      const unsigned short* __restrict__ vb,
                      const int* __restrict__ offsets,
                      const int* __restrict__ sorted_r,
                      unsigned short* __restrict__ acc_out, int n)
{
    const int lane = threadIdx.x & 63;
    const int wid  = threadIdx.x >> 6;
    const int node = blockIdx.x * 4 + wid;
    if (node >= n) return;

    const int s    = lane >> 2;          // edge slot 0..15
    const int sub  = lane & 3;           // head-pair 0..3
    const int hp   = lane >> 4;          // PV: head-pair of owned dims (head = lane>>3)
    const int hsel = (lane >> 3) & 1;    // PV: which head within the pair
    const int seg0 = __builtin_amdgcn_readfirstlane(offsets[node]);
    const int segL = __builtin_amdgcn_readfirstlane(offsets[node + 1]) - seg0;
    const int nch  = (segL + 15) >> 4;
    const int* __restrict__ sr = sorted_r + seg0;

    // q for heads 2sub, 2sub+1: 32 bf16 at element offset sub*32
    float qA[16], qB[16];
    {
        const uint4* p = reinterpret_cast<const uint4*>(&qb[(size_t)node * 128 + sub * 32]);
        uint4 u0 = p[0], u1 = p[1], u2 = p[2], u3 = p[3];
        unpack8(u0, qA); unpack8(u1, qA + 8);
        unpack8(u2, qB); unpack8(u3, qB + 8);
    }

    float acc0 = 0.f, acc1 = 0.f, ssumA = 0.f, ssumB = 0.f;

    uint4 kA0, kA1, kA2, kA3, kB0, kB1, kB2, kB3;
    unsigned int vA[16], vB[16];

    // prologue: chunk 0 (clamped addresses; ex=0 kills pad lanes)
    if (nch > 0) {
        int idx = (s < segL) ? s : (segL - 1);
        int rk  = sr[idx];
        const uint4* kp = reinterpret_cast<const uint4*>(&kb[(size_t)rk * 128 + sub * 32]);
        kA0 = kp[0]; kA1 = kp[1]; kA2 = kp[2]; kA3 = kp[3];
        int ec0 = (segL < 16) ? segL : 16;
        #pragma unroll
        for (int e = 0; e < 16; e++) {
            int re = sr[(e < ec0) ? e : (ec0 - 1)];   // uniform -> s_load
            vA[e] = *reinterpret_cast<const unsigned int*>(&vb[(size_t)re * 128 + 2 * lane]);
        }
    }

    auto step = [&](int c,
                    const uint4& ck0, const uint4& ck1, const uint4& ck2, const uint4& ck3,
                    const unsigned int (&cv)[16],
                    uint4& nk0, uint4& nk1, uint4& nk2, uint4& nk3,
                    unsigned int (&nv)[16]) {
        const int base = c << 4;
        // prefetch chunk c+1
        if (c + 1 < nch) {
            int nb   = base + 16;
            int nidx = nb + s;
            int rk   = sr[(nidx < segL) ? nidx : (segL - 1)];
            const uint4* kp = reinterpret_cast<const uint4*>(&kb[(size_t)rk * 128 + sub * 32]);
            nk0 = kp[0]; nk1 = kp[1]; nk2 = kp[2]; nk3 = kp[3];
            int ecn = segL - nb; if (ecn > 16) ecn = 16;
            #pragma unroll
            for (int e = 0; e < 16; e++) {
                int re = sr[nb + ((e < ecn) ? e : (ecn - 1))];
                nv[e] = *reinterpret_cast<const unsigned int*>(&vb[(size_t)re * 128 + 2 * lane]);
            }
        }
        // two full scores per lane
        float kf[8];
        float sAv = 0.f, sBv = 0.f;
        unpack8(ck0, kf);
        #pragma unroll
        for (int i = 0; i < 8; i++) sAv += qA[i] * kf[i];
        unpack8(ck1, kf);
        #pragma unroll
        for (int i = 0; i < 8; i++) sAv += qA[8 + i] * kf[i];
        unpack8(ck2, kf);
        #pragma unroll
        for (int i = 0; i < 8; i++) sBv += qB[i] * kf[i];
        unpack8(ck3, kf);
        #pragma unroll
        for (int i = 0; i < 8; i++) sBv += qB[8 + i] * kf[i];
        bool valid = (base + s) < segL;
        float exA = valid ? __expf(sAv * 0.25f) : 0.f;
        float exB = valid ? __expf(sBv * 0.25f) : 0.f;
        ssumA += exA; ssumB += exB;
        // PV: broadcast ex per (edge, head), FMA with prefetched v
        #pragma unroll
        for (int e = 0; e < 16; e++) {
            float eA = __shfl(exA, e * 4 + hp);
            float eB = __shfl(exB, e * 4 + hp);
            float exv = hsel ? eB : eA;
            acc0 += exv * bfbits2f((unsigned short)(cv[e] & 0xffffu));
            acc1 += exv * bfbits2f((unsigned short)(cv[e] >> 16));
        }
    };

    int c = 0;
    while (c < nch) {
        step(c, kA0, kA1, kA2, kA3, vA, kB0, kB1, kB2, kB3, vB); c++;
        if (c >= nch) break;
        step(c, kB0, kB1, kB2, kB3, vB, kA0, kA1, kA2, kA3, vA); c++;
    }

    // reduce ssum over edge slots (lane bits 2..5)
    ssumA += __shfl_xor(ssumA, 4);  ssumB += __shfl_xor(ssumB, 4);
    ssumA += __shfl_xor(ssumA, 8);  ssumB += __shfl_xor(ssumB, 8);
    ssumA += __shfl_xor(ssumA, 16); ssumB += __shfl_xor(ssumB, 16);
    ssumA += __shfl_xor(ssumA, 32); ssumB += __shfl_xor(ssumB, 32);
    float denA = __shfl(ssumA, hp);
    float denB = __shfl(ssumB, hp);
    float den  = (hsel ? denB : denA) + 1e-16f;
    float rd   = 1.0f / den;

    reinterpret_cast<unsigned int*>(acc_out)[(size_t)node * 64 + lane] =
        pack2bf(acc0 * rd, acc1 * rd);
}

// ---------- output GEMM: out[M,128] = accb(bf16) @ Wo.T + bo, fp32 out ----------
__global__ __launch_bounds__(256)
void out_gemm(const unsigned short* __restrict__ A, const unsigned short* __restrict__ Wb,
              const float* __restrict__ bias, float* __restrict__ O, int M)
{
    const int lane = threadIdx.x & 63;
    const int w    = threadIdx.x >> 6;
    const int r0   = blockIdx.x * 128 + w * 32;
    const int lr   = lane & 15;
    const int lk   = (lane >> 4) * 8;
    const int cq   = (lane >> 4) * 4;

    bh8 a[2][4];
    #pragma unroll
    for (int jt = 0; jt < 2; jt++) {
        int row = r0 + jt * 16 + lr; if (row >= M) row = M - 1;
        const unsigned short* ap = &A[(size_t)row * 128 + lk];
        #pragma unroll
        for (int ks = 0; ks < 4; ks++)
            a[jt][ks] = *reinterpret_cast<const bh8*>(ap + ks * 32);
    }

    f32x4 acc[2][8];
    #pragma unroll
    for (int jt = 0; jt < 2; jt++)
        #pragma unroll
        for (int it = 0; it < 8; it++)
            #pragma unroll
            for (int q = 0; q < 4; q++) acc[jt][it][q] = 0.f;

    #pragma unroll
    for (int ks = 0; ks < 4; ks++) {
        bh8 b[8];
        #pragma unroll
        for (int it = 0; it < 8; it++)
            b[it] = *reinterpret_cast<const bh8*>(
                &Wb[(size_t)(it * 16 + lr) * 128 + ks * 32 + lk]);
        #pragma unroll
        for (int jt = 0; jt < 2; jt++)
            #pragma unroll
            for (int it = 0; it < 8; it++)
                acc[jt][it] = __builtin_amdgcn_mfma_f32_16x16x32_bf16(
                    b[it], a[jt][ks], acc[jt][it], 0, 0, 0);
    }

    #pragma unroll
    for (int jt = 0; jt < 2; jt++) {
        int row = r0 + jt * 16 + lr;
        if (row >= M) continue;
        #pragma unroll
        for (int it = 0; it < 8; it++) {
            float4 b4 = *reinterpret_cast<const float4*>(&bias[it * 16 + cq]);
            float4 o;
            o.x = acc[jt][it][0] + b4.x;
            o.y = acc[jt][it][1] + b4.y;
            o.z = acc[jt][it][2] + b4.z;
            o.w = acc[jt][it][3] + b4.w;
            *reinterpret_cast<float4*>(&O[(size_t)row * 128 + it * 16 + cq]) = o;
        }
    }
}

// ---------- launch ----------
extern "C" void kernel_launch(void* const* d_in, const int* in_sizes, int n_in,
                              void* d_out, int out_size, void* d_ws, size_t ws_size,
                              hipStream_t stream)
{
    const float* feats = (const float*)d_in[0];
    const int*   ei    = (const int*)d_in[1];
    const float* Wq = (const float*)d_in[3];
    const float* bq = (const float*)d_in[4];
    const float* Wk = (const float*)d_in[5];
    const float* bk = (const float*)d_in[6];
    const float* Wv = (const float*)d_in[7];
    const float* bv = (const float*)d_in[8];
    const float* Wo = (const float*)d_in[9];
    const float* bo = (const float*)d_in[10];
    float* out = (float*)d_out;

    const int N = in_sizes[0] / 128;
    const int E = in_sizes[1] / 2;
    const int nb = (N + 1023) / 1024;

    char* ws = (char*)d_ws;
    size_t off = 0;
    auto alloc = [&](size_t bytes) -> void* {
        void* p = ws + off;
        off += (bytes + 255) & ~(size_t)255;
        return p;
    };
    unsigned short* qb   = (unsigned short*)alloc((size_t)N * 128 * 2);
    unsigned short* kb   = (unsigned short*)alloc((size_t)N * 128 * 2);
    unsigned short* vb   = (unsigned short*)alloc((size_t)N * 128 * 2);
    unsigned short* accb = (unsigned short*)alloc((size_t)N * 128 * 2);
    int* rank     = (int*)accb;   // alias: rank lifetime (hist->scatter) disjoint from accb
    int* counts   = (int*)alloc(((size_t)N + 1) * 4);
    int* offsets  = (int*)alloc(((size_t)N + 1) * 4);
    int* sorted_r = (int*)alloc((size_t)E * 4);
    int* blkSum   = (int*)alloc(256 * 4);
    int* blkOff   = (int*)alloc(256 * 4);
    unsigned short* Wqb = (unsigned short*)alloc(128 * 128 * 2);
    unsigned short* Wkb = (unsigned short*)alloc(128 * 128 * 2);
    unsigned short* Wvb = (unsigned short*)alloc(128 * 128 * 2);
    unsigned short* Wob = (unsigned short*)alloc(128 * 128 * 2);

    hipMemsetAsync(counts, 0, ((size_t)N + 1) * 4, stream);

    wconv_hist<<<64 + (E + 255) / 256, 256, 0, stream>>>(
        Wq, Wk, Wv, Wo, Wqb, Wkb, Wvb, Wob, ei, counts, rank, E);

    scan1_kernel<<<nb, 1024, 0, stream>>>(counts, offsets, blkSum, N);
    scan2_kernel<<<1, 64, 0, stream>>>(blkSum, blkOff, offsets, nb, N);
    scan3_kernel<<<nb, 1024, 0, stream>>>(offsets, blkOff, N);

    const int gx  = (N + 127) / 128;
    const int nsb = 1024;
    qkv_scatter<<<gx + nsb, 256, 0, stream>>>(feats, Wqb, bq, Wkb, bk, Wvb, bv,
                                              qb, kb, vb, N, gx,
                                              ei, offsets, rank, sorted_r, E, nsb);

    edge_attn_kernel<<<(N + 3) / 4, 256, 0, stream>>>(qb, kb, vb, offsets, sorted_r, accb, N);

    out_gemm<<<gx, 256, 0, stream>>>(accb, Wob, bo, out, N);
}

// Round 8
// 334.024 us; speedup vs baseline: 1.0163x; 1.0163x over previous
//
#include <hip/hip_runtime.h>
#include <hip/hip_bf16.h>

typedef __attribute__((ext_vector_type(8))) short bh8;
typedef __attribute__((ext_vector_type(4))) float f32x4;

__device__ __forceinline__ float bfbits2f(unsigned short s) {
    union { unsigned int u; float f; } cv;
    cv.u = ((unsigned int)s) << 16;
    return cv.f;
}
__device__ __forceinline__ unsigned short f2bfbits(float f) {
    union { float f; unsigned int u; } cv; cv.f = f;
    unsigned int u = cv.u;
    u += 0x7fffu + ((u >> 16) & 1u);   // round-to-nearest-even
    return (unsigned short)(u >> 16);
}
__device__ __forceinline__ unsigned int pack2bf(float a, float b) {
    return (unsigned int)f2bfbits(a) | (((unsigned int)f2bfbits(b)) << 16);
}

// load 8 consecutive fp32, convert to a bf16x8 MFMA fragment
__device__ __forceinline__ bh8 load_frag_f32(const float* __restrict__ p) {
    float4 f0 = *reinterpret_cast<const float4*>(p);
    float4 f1 = *reinterpret_cast<const float4*>(p + 4);
    bh8 r;
    r[0] = (short)f2bfbits(f0.x); r[1] = (short)f2bfbits(f0.y);
    r[2] = (short)f2bfbits(f0.z); r[3] = (short)f2bfbits(f0.w);
    r[4] = (short)f2bfbits(f1.x); r[5] = (short)f2bfbits(f1.y);
    r[6] = (short)f2bfbits(f1.z); r[7] = (short)f2bfbits(f1.w);
    return r;
}

// ---------- W conv (64 blocks) + histogram-with-packed-record (rest) ----------
// erec[e] = (r | rank<<17, c): r<2^17 (N<=131072), rank<2^14 (max degree)
__global__ __launch_bounds__(256)
void wconv_hist(const float* __restrict__ w0, const float* __restrict__ w1,
                const float* __restrict__ w2, const float* __restrict__ w3,
                unsigned short* __restrict__ o0, unsigned short* __restrict__ o1,
                unsigned short* __restrict__ o2, unsigned short* __restrict__ o3,
                const int* __restrict__ ei, int* __restrict__ counts,
                int2* __restrict__ erec, int E)
{
    if (blockIdx.x < 64) {
        const float* src[4] = {w0, w1, w2, w3};
        unsigned short* dst[4] = {o0, o1, o2, o3};
        const float* s = src[blockIdx.x >> 4];
        unsigned short* d = dst[blockIdx.x >> 4];
        int i = ((blockIdx.x & 15) * 256 + threadIdx.x) * 4;
        float4 f = *reinterpret_cast<const float4*>(&s[i]);
        uint2 p;
        p.x = pack2bf(f.x, f.y);
        p.y = pack2bf(f.z, f.w);
        *reinterpret_cast<uint2*>(&d[i]) = p;
        return;
    }
    int e = (blockIdx.x - 64) * 256 + threadIdx.x;
    if (e < E) {
        int2 rc = reinterpret_cast<const int2*>(ei)[e];
        unsigned int rk = (unsigned int)atomicAdd(&counts[rc.y], 1);
        erec[e] = make_int2((int)((unsigned int)rc.x | (rk << 17)), rc.y);
    }
}

// ---------- scans ----------
__device__ __forceinline__ int wave_incl_scan(int v, int lane) {
    #pragma unroll
    for (int off = 1; off < 64; off <<= 1) {
        int y = __shfl_up(v, off);
        if (lane >= off) v += y;
    }
    return v;
}

__global__ __launch_bounds__(1024)
void scan1_kernel(const int* __restrict__ counts, int* __restrict__ offs,
                  int* __restrict__ blkSum, int n)
{
    __shared__ int wsum[16];
    __shared__ int woff[16];
    const int t = threadIdx.x, lane = t & 63, w = t >> 6;
    int i = blockIdx.x * 1024 + t;
    int x = (i < n) ? counts[i] : 0;
    int v = wave_incl_scan(x, lane);
    if (lane == 63) wsum[w] = v;
    __syncthreads();
    if (t == 0) {
        int s = 0;
        #pragma unroll
        for (int j = 0; j < 16; j++) { int tmp = wsum[j]; woff[j] = s; s += tmp; }
        blkSum[blockIdx.x] = s;
    }
    __syncthreads();
    if (i < n) offs[i] = woff[w] + v - x;
}

__global__ void scan2_kernel(const int* __restrict__ blkSum, int* __restrict__ blkOff,
                             int* __restrict__ offs, int nb, int n)
{
    const int lane = threadIdx.x;   // 64 threads
    int carry = 0;
    for (int base = 0; base < nb; base += 64) {
        int x = (base + lane < nb) ? blkSum[base + lane] : 0;
        int v = wave_incl_scan(x, lane);
        if (base + lane < nb) blkOff[base + lane] = carry + v - x;
        carry += __shfl(v, 63);
    }
    if (lane == 0) offs[n] = carry;
}

__global__ __launch_bounds__(1024)
void scan3_kernel(int* __restrict__ offs, const int* __restrict__ blkOff, int n)
{
    int i = blockIdx.x * 1024 + threadIdx.x;
    if (i < n) offs[i] += blkOff[blockIdx.x];
}

// ---------- fused QKV GEMM + XCD-local atomic-free scatter (blockIdx split) ----------
// scatter blocks: group g = blockIdx&7 (heuristic XCD id) handles dests in
// [g*segN, (g+1)*segN) only -> its sorted_r window (~800KB) lives in its own L2,
// lines accumulate all writes locally and evict full exactly once.
__global__ __launch_bounds__(256)
void qkv_scatter(const float* __restrict__ A,
                 const unsigned short* __restrict__ Wqb, const float* __restrict__ bq,
                 const unsigned short* __restrict__ Wkb, const float* __restrict__ bk,
                 const unsigned short* __restrict__ Wvb, const float* __restrict__ bv,
                 unsigned short* __restrict__ Oq, unsigned short* __restrict__ Ok,
                 unsigned short* __restrict__ Ov, int M, int gx,
                 const int2* __restrict__ erec, const int* __restrict__ offsets,
                 int* __restrict__ sorted_r, int E, int nsb)
{
    if (blockIdx.x >= (unsigned)gx) {
        const int grp  = blockIdx.x & 7;           // XCD heuristic (absolute id)
        const int j    = blockIdx.x - gx;          // 0..nsb-1
        const int big  = j >> 3;                   // block index within group
        const int nbg  = nsb >> 3;                 // blocks per group
        const int segN = (M + 7) >> 3;
        const int lo   = grp * segN;
        const int hi   = (lo + segN < M) ? (lo + segN) : M;
        const int stride = nbg * 256;
        for (int e = big * 256 + threadIdx.x; e < E; e += stride) {
            int2 rec = erec[e];
            if (rec.y >= lo && rec.y < hi) {
                unsigned int rx = (unsigned int)rec.x;
                sorted_r[offsets[rec.y] + (int)(rx >> 17)] = (int)(rx & 0x1FFFFu);
            }
        }
        return;
    }

    const int lane = threadIdx.x & 63;
    const int w    = threadIdx.x >> 6;
    const int r0   = blockIdx.x * 128 + w * 32;
    const int lr   = lane & 15;
    const int lk   = (lane >> 4) * 8;
    const int cq   = (lane >> 4) * 4;

    bh8 a[2][4];
    #pragma unroll
    for (int jt = 0; jt < 2; jt++) {
        int row = r0 + jt * 16 + lr; if (row >= M) row = M - 1;
        const float* ap = &A[(size_t)row * 128 + lk];
        #pragma unroll
        for (int ks = 0; ks < 4; ks++) a[jt][ks] = load_frag_f32(ap + ks * 32);
    }

    const unsigned short* Ws[3] = {Wqb, Wkb, Wvb};
    const float* Bs[3] = {bq, bk, bv};
    unsigned short* Os[3] = {Oq, Ok, Ov};

    #pragma unroll
    for (int wsel = 0; wsel < 3; wsel++) {
        const unsigned short* W = Ws[wsel];
        f32x4 acc[2][8];
        #pragma unroll
        for (int jt = 0; jt < 2; jt++)
            #pragma unroll
            for (int it = 0; it < 8; it++)
                #pragma unroll
                for (int q = 0; q < 4; q++) acc[jt][it][q] = 0.f;

        #pragma unroll
        for (int ks = 0; ks < 4; ks++) {
            bh8 b[8];
            #pragma unroll
            for (int it = 0; it < 8; it++)
                b[it] = *reinterpret_cast<const bh8*>(
                    &W[(size_t)(it * 16 + lr) * 128 + ks * 32 + lk]);
            #pragma unroll
            for (int jt = 0; jt < 2; jt++)
                #pragma unroll
                for (int it = 0; it < 8; it++)
                    acc[jt][it] = __builtin_amdgcn_mfma_f32_16x16x32_bf16(
                        b[it], a[jt][ks], acc[jt][it], 0, 0, 0);
        }

        const float* bias = Bs[wsel];
        unsigned short* O = Os[wsel];
        #pragma unroll
        for (int jt = 0; jt < 2; jt++) {
            int row = r0 + jt * 16 + lr;
            if (row >= M) continue;
            #pragma unroll
            for (int it = 0; it < 8; it++) {
                float4 b4 = *reinterpret_cast<const float4*>(&bias[it * 16 + cq]);
                uint2 pk;
                pk.x = pack2bf(acc[jt][it][0] + b4.x, acc[jt][it][1] + b4.y);
                pk.y = pack2bf(acc[jt][it][2] + b4.z, acc[jt][it][3] + b4.w);
                *reinterpret_cast<uint2*>(&O[(size_t)row * 128 + it * 16 + cq]) = pk;
            }
        }
    }
}

// ---------- edge attention: one wave per destination node, pipelined (round-5) ----------
__global__ __launch_bounds__(256)
void edge_attn_kernel(const unsigned short* __restrict__ qb,
                      const unsigned short* __restrict__ kb,
                      const unsigned short* __restrict__ vb,
                      const int* __restrict__ offsets,
                      const int* __restrict__ sorted_r,
                      unsigned short* __restrict__ acc_out, int n)
{
    const int lane = threadIdx.x & 63;
    const int wid  = threadIdx.x >> 6;
    const int node = blockIdx.x * 4 + wid;
    if (node >= n) return;

    const int h    = lane & 7;    // head (score phase)
    const int eloc = lane >> 3;   // k-edge slot == head of owned dims (2*lane)
    const int seg0 = __builtin_amdgcn_readfirstlane(offsets[node]);
    const int segL = __builtin_amdgcn_readfirstlane(offsets[node + 1]) - seg0;
    const int nch  = (segL + 7) >> 3;
    const int* __restrict__ sr = sorted_r + seg0;

    float qf[16];
    {
        const uint4* p = reinterpret_cast<const uint4*>(&qb[(size_t)node * 128 + h * 16]);
        uint4 u0 = p[0], u1 = p[1];
        unsigned int uu[8] = {u0.x, u0.y, u0.z, u0.w, u1.x, u1.y, u1.z, u1.w};
        #pragma unroll
        for (int i = 0; i < 8; i++) {
            qf[2 * i]     = bfbits2f((unsigned short)(uu[i] & 0xffffu));
            qf[2 * i + 1] = bfbits2f((unsigned short)(uu[i] >> 16));
        }
    }

    float acc0 = 0.f, acc1 = 0.f, ssum = 0.f;

    uint4 kA0, kA1, kB0, kB1;
    unsigned int vA[8], vB[8];

    if (nch > 0) {
        int idx = (eloc < segL) ? eloc : (segL - 1);
        int rk  = sr[idx];
        const uint4* kp = reinterpret_cast<const uint4*>(&kb[(size_t)rk * 128 + h * 16]);
        kA0 = kp[0]; kA1 = kp[1];
        int ec0 = (segL < 8) ? segL : 8;
        #pragma unroll
        for (int e = 0; e < 8; e++) {
            int re = sr[(e < ec0) ? e : (ec0 - 1)];   // uniform -> s_load
            vA[e] = *reinterpret_cast<const unsigned int*>(&vb[(size_t)re * 128 + 2 * lane]);
        }
    }

    auto step = [&](int c, const uint4& ck0, const uint4& ck1, const unsigned int (&cv)[8],
                    uint4& nk0, uint4& nk1, unsigned int (&nv)[8]) {
        const int base = c << 3;
        if (c + 1 < nch) {
            int nb   = base + 8;
            int nidx = nb + eloc;
            int rk   = sr[(nidx < segL) ? nidx : (segL - 1)];
            const uint4* kp = reinterpret_cast<const uint4*>(&kb[(size_t)rk * 128 + h * 16]);
            nk0 = kp[0]; nk1 = kp[1];
            int ecn = segL - nb; if (ecn > 8) ecn = 8;
            #pragma unroll
            for (int e = 0; e < 8; e++) {
                int re = sr[nb + ((e < ecn) ? e : (ecn - 1))];
                nv[e] = *reinterpret_cast<const unsigned int*>(&vb[(size_t)re * 128 + 2 * lane]);
            }
        }
        unsigned int uu[8] = {ck0.x, ck0.y, ck0.z, ck0.w, ck1.x, ck1.y, ck1.z, ck1.w};
        float s = 0.f;
        #pragma unroll
        for (int i = 0; i < 8; i++) {
            s += qf[2 * i]     * bfbits2f((unsigned short)(uu[i] & 0xffffu));
            s += qf[2 * i + 1] * bfbits2f((unsigned short)(uu[i] >> 16));
        }
        float ex = (base + eloc < segL) ? __expf(s * 0.25f) : 0.f;
        ssum += ex;
        #pragma unroll
        for (int e = 0; e < 8; e++) {
            float exv = __shfl(ex, e * 8 + eloc);
            acc0 += exv * bfbits2f((unsigned short)(cv[e] & 0xffffu));
            acc1 += exv * bfbits2f((unsigned short)(cv[e] >> 16));
        }
    };

    int c = 0;
    while (c < nch) {
        step(c, kA0, kA1, vA, kB0, kB1, vB); c++;
        if (c >= nch) break;
        step(c, kB0, kB1, vB, kA0, kA1, vA); c++;
    }

    ssum += __shfl_xor(ssum, 8);
    ssum += __shfl_xor(ssum, 16);
    ssum += __shfl_xor(ssum, 32);
    float den = __shfl(ssum, lane >> 3) + 1e-16f;
    float rd  = 1.0f / den;

    reinterpret_cast<unsigned int*>(acc_out)[(size_t)node * 64 + lane] =
        pack2bf(acc0 * rd, acc1 * rd);
}

// ---------- output GEMM: out[M,128] = accb(bf16) @ Wo.T + bo, fp32 out ----------
__global__ __launch_bounds__(256)
void out_gemm(const unsigned short* __restrict__ A, const unsigned short* __restrict__ Wb,
              const float* __restrict__ bias, float* __restrict__ O, int M)
{
    const int lane = threadIdx.x & 63;
    const int w    = threadIdx.x >> 6;
    const int r0   = blockIdx.x * 128 + w * 32;
    const int lr   = lane & 15;
    const int lk   = (lane >> 4) * 8;
    const int cq   = (lane >> 4) * 4;

    bh8 a[2][4];
    #pragma unroll
    for (int jt = 0; jt < 2; jt++) {
        int row = r0 + jt * 16 + lr; if (row >= M) row = M - 1;
        const unsigned short* ap = &A[(size_t)row * 128 + lk];
        #pragma unroll
        for (int ks = 0; ks < 4; ks++)
            a[jt][ks] = *reinterpret_cast<const bh8*>(ap + ks * 32);
    }

    f32x4 acc[2][8];
    #pragma unroll
    for (int jt = 0; jt < 2; jt++)
        #pragma unroll
        for (int it = 0; it < 8; it++)
            #pragma unroll
            for (int q = 0; q < 4; q++) acc[jt][it][q] = 0.f;

    #pragma unroll
    for (int ks = 0; ks < 4; ks++) {
        bh8 b[8];
        #pragma unroll
        for (int it = 0; it < 8; it++)
            b[it] = *reinterpret_cast<const bh8*>(
                &Wb[(size_t)(it * 16 + lr) * 128 + ks * 32 + lk]);
        #pragma unroll
        for (int jt = 0; jt < 2; jt++)
            #pragma unroll
            for (int it = 0; it < 8; it++)
                acc[jt][it] = __builtin_amdgcn_mfma_f32_16x16x32_bf16(
                    b[it], a[jt][ks], acc[jt][it], 0, 0, 0);
    }

    #pragma unroll
    for (int jt = 0; jt < 2; jt++) {
        int row = r0 + jt * 16 + lr;
        if (row >= M) continue;
        #pragma unroll
        for (int it = 0; it < 8; it++) {
            float4 b4 = *reinterpret_cast<const float4*>(&bias[it * 16 + cq]);
            float4 o;
            o.x = acc[jt][it][0] + b4.x;
            o.y = acc[jt][it][1] + b4.y;
            o.z = acc[jt][it][2] + b4.z;
            o.w = acc[jt][it][3] + b4.w;
            *reinterpret_cast<float4*>(&O[(size_t)row * 128 + it * 16 + cq]) = o;
        }
    }
}

// ---------- launch ----------
extern "C" void kernel_launch(void* const* d_in, const int* in_sizes, int n_in,
                              void* d_out, int out_size, void* d_ws, size_t ws_size,
                              hipStream_t stream)
{
    const float* feats = (const float*)d_in[0];
    const int*   ei    = (const int*)d_in[1];
    const float* Wq = (const float*)d_in[3];
    const float* bq = (const float*)d_in[4];
    const float* Wk = (const float*)d_in[5];
    const float* bk = (const float*)d_in[6];
    const float* Wv = (const float*)d_in[7];
    const float* bv = (const float*)d_in[8];
    const float* Wo = (const float*)d_in[9];
    const float* bo = (const float*)d_in[10];
    float* out = (float*)d_out;

    const int N = in_sizes[0] / 128;
    const int E = in_sizes[1] / 2;
    const int nb = (N + 1023) / 1024;

    char* ws = (char*)d_ws;
    size_t off = 0;
    auto alloc = [&](size_t bytes) -> void* {
        void* p = ws + off;
        off += (bytes + 255) & ~(size_t)255;
        return p;
    };
    unsigned short* qb   = (unsigned short*)alloc((size_t)N * 128 * 2);
    unsigned short* kb   = (unsigned short*)alloc((size_t)N * 128 * 2);
    unsigned short* vb   = (unsigned short*)alloc((size_t)N * 128 * 2);
    unsigned short* accb = (unsigned short*)alloc((size_t)N * 128 * 2);
    int2* erec    = (int2*)accb;   // alias: erec lifetime (hist->scatter) disjoint from accb
    int* counts   = (int*)alloc(((size_t)N + 1) * 4);
    int* offsets  = (int*)alloc(((size_t)N + 1) * 4);
    int* sorted_r = (int*)alloc((size_t)E * 4);
    int* blkSum   = (int*)alloc(256 * 4);
    int* blkOff   = (int*)alloc(256 * 4);
    unsigned short* Wqb = (unsigned short*)alloc(128 * 128 * 2);
    unsigned short* Wkb = (unsigned short*)alloc(128 * 128 * 2);
    unsigned short* Wvb = (unsigned short*)alloc(128 * 128 * 2);
    unsigned short* Wob = (unsigned short*)alloc(128 * 128 * 2);

    hipMemsetAsync(counts, 0, ((size_t)N + 1) * 4, stream);

    wconv_hist<<<64 + (E + 255) / 256, 256, 0, stream>>>(
        Wq, Wk, Wv, Wo, Wqb, Wkb, Wvb, Wob, ei, counts, erec, E);

    scan1_kernel<<<nb, 1024, 0, stream>>>(counts, offsets, blkSum, N);
    scan2_kernel<<<1, 64, 0, stream>>>(blkSum, blkOff, offsets, nb, N);
    scan3_kernel<<<nb, 1024, 0, stream>>>(offsets, blkOff, N);

    const int gx  = (N + 127) / 128;
    const int nsb = 2048;   // multiple of 8 (XCD groups)
    qkv_scatter<<<gx + nsb, 256, 0, stream>>>(feats, Wqb, bq, Wkb, bk, Wvb, bv,
                                              qb, kb, vb, N, gx,
                                              erec, offsets, sorted_r, E, nsb);

    edge_attn_kernel<<<(N + 3) / 4, 256, 0, stream>>>(qb, kb, vb, offsets, sorted_r, accb, N);

    out_gemm<<<gx, 256, 0, stream>>>(accb, Wob, bo, out, N);
}

// Round 9
// 311.841 us; speedup vs baseline: 1.0886x; 1.0711x over previous
//
#include <hip/hip_runtime.h>
#include <hip/hip_bf16.h>

typedef __attribute__((ext_vector_type(8))) short bh8;
typedef __attribute__((ext_vector_type(4))) float f32x4;

#define TILE_SHIFT 8            // 256 dest-nodes per tile
#define MAXTILES 512            // supports N up to 131072 (r fits 17 bits)

__device__ __forceinline__ float bfbits2f(unsigned short s) {
    union { unsigned int u; float f; } cv;
    cv.u = ((unsigned int)s) << 16;
    return cv.f;
}
__device__ __forceinline__ unsigned short f2bfbits(float f) {
    union { float f; unsigned int u; } cv; cv.f = f;
    unsigned int u = cv.u;
    u += 0x7fffu + ((u >> 16) & 1u);   // round-to-nearest-even
    return (unsigned short)(u >> 16);
}
__device__ __forceinline__ unsigned int pack2bf(float a, float b) {
    return (unsigned int)f2bfbits(a) | (((unsigned int)f2bfbits(b)) << 16);
}

// load 8 consecutive fp32, convert to a bf16x8 MFMA fragment
__device__ __forceinline__ bh8 load_frag_f32(const float* __restrict__ p) {
    float4 f0 = *reinterpret_cast<const float4*>(p);
    float4 f1 = *reinterpret_cast<const float4*>(p + 4);
    bh8 r;
    r[0] = (short)f2bfbits(f0.x); r[1] = (short)f2bfbits(f0.y);
    r[2] = (short)f2bfbits(f0.z); r[3] = (short)f2bfbits(f0.w);
    r[4] = (short)f2bfbits(f1.x); r[5] = (short)f2bfbits(f1.y);
    r[6] = (short)f2bfbits(f1.z); r[7] = (short)f2bfbits(f1.w);
    return r;
}

// ---------- W conv (64 blocks) + pure histogram (rest) ----------
__global__ __launch_bounds__(256)
void wconv_hist(const float* __restrict__ w0, const float* __restrict__ w1,
                const float* __restrict__ w2, const float* __restrict__ w3,
                unsigned short* __restrict__ o0, unsigned short* __restrict__ o1,
                unsigned short* __restrict__ o2, unsigned short* __restrict__ o3,
                const int* __restrict__ ei, int* __restrict__ counts, int E)
{
    if (blockIdx.x < 64) {
        const float* src[4] = {w0, w1, w2, w3};
        unsigned short* dst[4] = {o0, o1, o2, o3};
        const float* s = src[blockIdx.x >> 4];
        unsigned short* d = dst[blockIdx.x >> 4];
        int i = ((blockIdx.x & 15) * 256 + threadIdx.x) * 4;
        float4 f = *reinterpret_cast<const float4*>(&s[i]);
        uint2 p;
        p.x = pack2bf(f.x, f.y);
        p.y = pack2bf(f.z, f.w);
        *reinterpret_cast<uint2*>(&d[i]) = p;
        return;
    }
    int e = (blockIdx.x - 64) * 256 + threadIdx.x;
    if (e < E) {
        int2 rc = reinterpret_cast<const int2*>(ei)[e];
        atomicAdd(&counts[rc.y], 1);
    }
}

// ---------- scans ----------
__device__ __forceinline__ int wave_incl_scan(int v, int lane) {
    #pragma unroll
    for (int off = 1; off < 64; off <<= 1) {
        int y = __shfl_up(v, off);
        if (lane >= off) v += y;
    }
    return v;
}

__global__ __launch_bounds__(1024)
void scan1_kernel(const int* __restrict__ counts, int* __restrict__ offs,
                  int* __restrict__ blkSum, int n)
{
    __shared__ int wsum[16];
    __shared__ int woff[16];
    const int t = threadIdx.x, lane = t & 63, w = t >> 6;
    int i = blockIdx.x * 1024 + t;
    int x = (i < n) ? counts[i] : 0;
    int v = wave_incl_scan(x, lane);
    if (lane == 63) wsum[w] = v;
    __syncthreads();
    if (t == 0) {
        int s = 0;
        #pragma unroll
        for (int j = 0; j < 16; j++) { int tmp = wsum[j]; woff[j] = s; s += tmp; }
        blkSum[blockIdx.x] = s;
    }
    __syncthreads();
    if (i < n) offs[i] = woff[w] + v - x;
}

__global__ void scan2_kernel(const int* __restrict__ blkSum, int* __restrict__ blkOff,
                             int* __restrict__ offs, int nb, int n)
{
    const int lane = threadIdx.x;   // 64 threads
    int carry = 0;
    for (int base = 0; base < nb; base += 64) {
        int x = (base + lane < nb) ? blkSum[base + lane] : 0;
        int v = wave_incl_scan(x, lane);
        if (base + lane < nb) blkOff[base + lane] = carry + v - x;
        carry += __shfl(v, 63);
    }
    if (lane == 0) offs[n] = carry;
}

__global__ __launch_bounds__(1024)
void scan3_kernel(int* __restrict__ offs, const int* __restrict__ blkOff, int n)
{
    int i = blockIdx.x * 1024 + threadIdx.x;
    if (i < n) offs[i] += blkOff[blockIdx.x];
}

// ---------- fused QKV GEMM + tile-binning (blockIdx split) ----------
// blocks [0,gx): MFMA QKV GEMM. blocks [gx,gx+nsb): bin edges by dst-tile into
// ebuf as packed 4B recs (r | c_local<<17), grouped runs per tile, placed at
// offsets[tile<<8] + per-tile global ticket.
__global__ __launch_bounds__(256)
void qkv_bin(const float* __restrict__ A,
             const unsigned short* __restrict__ Wqb, const float* __restrict__ bq,
             const unsigned short* __restrict__ Wkb, const float* __restrict__ bk,
             const unsigned short* __restrict__ Wvb, const float* __restrict__ bv,
             unsigned short* __restrict__ Oq, unsigned short* __restrict__ Ok,
             unsigned short* __restrict__ Ov, int M, int gx,
             const int* __restrict__ ei, const int* __restrict__ offsets,
             int* __restrict__ bfill, unsigned int* __restrict__ ebuf,
             int E, int nsb)
{
    __shared__ int hcnt[MAXTILES];
    __shared__ int hbase[MAXTILES];

    if (blockIdx.x >= (unsigned)gx) {
        const int ntiles = (M + (1 << TILE_SHIFT) - 1) >> TILE_SHIFT;
        const int sb = blockIdx.x - gx;
        int chunk0 = sb * 4096;
        if (chunk0 < E) {
            for (int i = threadIdx.x; i < ntiles; i += 256) hcnt[i] = 0;
            __syncthreads();
            unsigned int pk[16]; int lrk[16];
            #pragma unroll
            for (int j = 0; j < 16; j++) {
                int e = chunk0 + j * 256 + threadIdx.x;
                if (e < E) {
                    int2 rc = reinterpret_cast<const int2*>(ei)[e];
                    pk[j] = (unsigned int)rc.x | (((unsigned int)rc.y & 255u) << 17);
                    lrk[j] = atomicAdd(&hcnt[rc.y >> TILE_SHIFT], 1);
                } else pk[j] = 0xFFFFFFFFu;
            }
            __syncthreads();
            for (int b = threadIdx.x; b < ntiles; b += 256) {
                int cnt = hcnt[b];
                int gb = cnt ? atomicAdd(&bfill[b], cnt) : 0;
                hbase[b] = offsets[b << TILE_SHIFT] + gb;
            }
            __syncthreads();
            #pragma unroll
            for (int j = 0; j < 16; j++) {
                int e = chunk0 + j * 256 + threadIdx.x;
                if (e < E) {
                    int2 rc = reinterpret_cast<const int2*>(ei)[e];  // L2-hot re-read
                    ebuf[hbase[rc.y >> TILE_SHIFT] + lrk[j]] = pk[j];
                }
            }
        }
        return;
    }

    // ---- QKV GEMM path ----
    const int lane = threadIdx.x & 63;
    const int w    = threadIdx.x >> 6;
    const int r0   = blockIdx.x * 128 + w * 32;
    const int lr   = lane & 15;
    const int lk   = (lane >> 4) * 8;
    const int cq   = (lane >> 4) * 4;

    bh8 a[2][4];
    #pragma unroll
    for (int jt = 0; jt < 2; jt++) {
        int row = r0 + jt * 16 + lr; if (row >= M) row = M - 1;
        const float* ap = &A[(size_t)row * 128 + lk];
        #pragma unroll
        for (int ks = 0; ks < 4; ks++) a[jt][ks] = load_frag_f32(ap + ks * 32);
    }

    const unsigned short* Ws[3] = {Wqb, Wkb, Wvb};
    const float* Bs[3] = {bq, bk, bv};
    unsigned short* Os[3] = {Oq, Ok, Ov};

    #pragma unroll
    for (int wsel = 0; wsel < 3; wsel++) {
        const unsigned short* W = Ws[wsel];
        f32x4 acc[2][8];
        #pragma unroll
        for (int jt = 0; jt < 2; jt++)
            #pragma unroll
            for (int it = 0; it < 8; it++)
                #pragma unroll
                for (int q = 0; q < 4; q++) acc[jt][it][q] = 0.f;

        #pragma unroll
        for (int ks = 0; ks < 4; ks++) {
            bh8 b[8];
            #pragma unroll
            for (int it = 0; it < 8; it++)
                b[it] = *reinterpret_cast<const bh8*>(
                    &W[(size_t)(it * 16 + lr) * 128 + ks * 32 + lk]);
            #pragma unroll
            for (int jt = 0; jt < 2; jt++)
                #pragma unroll
                for (int it = 0; it < 8; it++)
                    acc[jt][it] = __builtin_amdgcn_mfma_f32_16x16x32_bf16(
                        b[it], a[jt][ks], acc[jt][it], 0, 0, 0);
        }

        const float* bias = Bs[wsel];
        unsigned short* O = Os[wsel];
        #pragma unroll
        for (int jt = 0; jt < 2; jt++) {
            int row = r0 + jt * 16 + lr;
            if (row >= M) continue;
            #pragma unroll
            for (int it = 0; it < 8; it++) {
                float4 b4 = *reinterpret_cast<const float4*>(&bias[it * 16 + cq]);
                uint2 pk;
                pk.x = pack2bf(acc[jt][it][0] + b4.x, acc[jt][it][1] + b4.y);
                pk.y = pack2bf(acc[jt][it][2] + b4.z, acc[jt][it][3] + b4.w);
                *reinterpret_cast<uint2*>(&O[(size_t)row * 128 + it * 16 + cq]) = pk;
            }
        }
    }
}

// ---------- tile-local sort: one block per 256-node tile, LDS tickets ----------
// Reads coalesced; writes land in the tile's contiguous sorted_r window
// (~16KB, L2-resident during the block's life -> full-line evictions).
__global__ __launch_bounds__(256)
void tile_sort(const unsigned int* __restrict__ ebuf, const int* __restrict__ offsets,
               int* __restrict__ sorted_r, int N)
{
    __shared__ int lfill[1 << TILE_SHIFT];
    const int n0 = blockIdx.x << TILE_SHIFT;
    int n1 = n0 + (1 << TILE_SHIFT); if (n1 > N) n1 = N;
    const int lo = offsets[n0];
    const int hi = offsets[n1];
    for (int c = threadIdx.x; c < (1 << TILE_SHIFT); c += 256) lfill[c] = 0;
    __syncthreads();
    for (int i = lo + threadIdx.x; i < hi; i += 256) {
        unsigned int rec = ebuf[i];
        int c = (int)(rec >> 17);
        int pos = offsets[n0 + c] + atomicAdd(&lfill[c], 1);
        sorted_r[pos] = (int)(rec & 0x1FFFFu);
    }
}

// ---------- edge attention: one wave per destination node, pipelined ----------
__global__ __launch_bounds__(256)
void edge_attn_kernel(const unsigned short* __restrict__ qb,
                      const unsigned short* __restrict__ kb,
                      const unsigned short* __restrict__ vb,
                      const int* __restrict__ offsets,
                      const int* __restrict__ sorted_r,
                      unsigned short* __restrict__ acc_out, int n)
{
    const int lane = threadIdx.x & 63;
    const int wid  = threadIdx.x >> 6;
    const int node = blockIdx.x * 4 + wid;
    if (node >= n) return;

    const int h    = lane & 7;    // head (score phase)
    const int eloc = lane >> 3;   // k-edge slot == head of owned dims (2*lane)
    const int seg0 = __builtin_amdgcn_readfirstlane(offsets[node]);
    const int segL = __builtin_amdgcn_readfirstlane(offsets[node + 1]) - seg0;
    const int nch  = (segL + 7) >> 3;
    const int* __restrict__ sr = sorted_r + seg0;

    float qf[16];
    {
        const uint4* p = reinterpret_cast<const uint4*>(&qb[(size_t)node * 128 + h * 16]);
        uint4 u0 = p[0], u1 = p[1];
        unsigned int uu[8] = {u0.x, u0.y, u0.z, u0.w, u1.x, u1.y, u1.z, u1.w};
        #pragma unroll
        for (int i = 0; i < 8; i++) {
            qf[2 * i]     = bfbits2f((unsigned short)(uu[i] & 0xffffu));
            qf[2 * i + 1] = bfbits2f((unsigned short)(uu[i] >> 16));
        }
    }

    float acc0 = 0.f, acc1 = 0.f, ssum = 0.f;

    uint4 kA0, kA1, kB0, kB1;
    unsigned int vA[8], vB[8];

    if (nch > 0) {
        int idx = (eloc < segL) ? eloc : (segL - 1);
        int rk  = sr[idx];
        const uint4* kp = reinterpret_cast<const uint4*>(&kb[(size_t)rk * 128 + h * 16]);
        kA0 = kp[0]; kA1 = kp[1];
        int ec0 = (segL < 8) ? segL : 8;
        #pragma unroll
        for (int e = 0; e < 8; e++) {
            int re = sr[(e < ec0) ? e : (ec0 - 1)];   // uniform -> s_load
            vA[e] = *reinterpret_cast<const unsigned int*>(&vb[(size_t)re * 128 + 2 * lane]);
        }
    }

    auto step = [&](int c, const uint4& ck0, const uint4& ck1, const unsigned int (&cv)[8],
                    uint4& nk0, uint4& nk1, unsigned int (&nv)[8]) {
        const int base = c << 3;
        if (c + 1 < nch) {
            int nb   = base + 8;
            int nidx = nb + eloc;
            int rk   = sr[(nidx < segL) ? nidx : (segL - 1)];
            const uint4* kp = reinterpret_cast<const uint4*>(&kb[(size_t)rk * 128 + h * 16]);
            nk0 = kp[0]; nk1 = kp[1];
            int ecn = segL - nb; if (ecn > 8) ecn = 8;
            #pragma unroll
            for (int e = 0; e < 8; e++) {
                int re = sr[nb + ((e < ecn) ? e : (ecn - 1))];
                nv[e] = *reinterpret_cast<const unsigned int*>(&vb[(size_t)re * 128 + 2 * lane]);
            }
        }
        unsigned int uu[8] = {ck0.x, ck0.y, ck0.z, ck0.w, ck1.x, ck1.y, ck1.z, ck1.w};
        float s = 0.f;
        #pragma unroll
        for (int i = 0; i < 8; i++) {
            s += qf[2 * i]     * bfbits2f((unsigned short)(uu[i] & 0xffffu));
            s += qf[2 * i + 1] * bfbits2f((unsigned short)(uu[i] >> 16));
        }
        float ex = (base + eloc < segL) ? __expf(s * 0.25f) : 0.f;
        ssum += ex;
        #pragma unroll
        for (int e = 0; e < 8; e++) {
            float exv = __shfl(ex, e * 8 + eloc);
            acc0 += exv * bfbits2f((unsigned short)(cv[e] & 0xffffu));
            acc1 += exv * bfbits2f((unsigned short)(cv[e] >> 16));
        }
    };

    int c = 0;
    while (c < nch) {
        step(c, kA0, kA1, vA, kB0, kB1, vB); c++;
        if (c >= nch) break;
        step(c, kB0, kB1, vB, kA0, kA1, vA); c++;
    }

    ssum += __shfl_xor(ssum, 8);
    ssum += __shfl_xor(ssum, 16);
    ssum += __shfl_xor(ssum, 32);
    float den = __shfl(ssum, lane >> 3) + 1e-16f;
    float rd  = 1.0f / den;

    reinterpret_cast<unsigned int*>(acc_out)[(size_t)node * 64 + lane] =
        pack2bf(acc0 * rd, acc1 * rd);
}

// ---------- output GEMM: out[M,128] = accb(bf16) @ Wo.T + bo, fp32 out ----------
__global__ __launch_bounds__(256)
void out_gemm(const unsigned short* __restrict__ A, const unsigned short* __restrict__ Wb,
              const float* __restrict__ bias, float* __restrict__ O, int M)
{
    const int lane = threadIdx.x & 63;
    const int w    = threadIdx.x >> 6;
    const int r0   = blockIdx.x * 128 + w * 32;
    const int lr   = lane & 15;
    const int lk   = (lane >> 4) * 8;
    const int cq   = (lane >> 4) * 4;

    bh8 a[2][4];
    #pragma unroll
    for (int jt = 0; jt < 2; jt++) {
        int row = r0 + jt * 16 + lr; if (row >= M) row = M - 1;
        const unsigned short* ap = &A[(size_t)row * 128 + lk];
        #pragma unroll
        for (int ks = 0; ks < 4; ks++)
            a[jt][ks] = *reinterpret_cast<const bh8*>(ap + ks * 32);
    }

    f32x4 acc[2][8];
    #pragma unroll
    for (int jt = 0; jt < 2; jt++)
        #pragma unroll
        for (int it = 0; it < 8; it++)
            #pragma unroll
            for (int q = 0; q < 4; q++) acc[jt][it][q] = 0.f;

    #pragma unroll
    for (int ks = 0; ks < 4; ks++) {
        bh8 b[8];
        #pragma unroll
        for (int it = 0; it < 8; it++)
            b[it] = *reinterpret_cast<const bh8*>(
                &Wb[(size_t)(it * 16 + lr) * 128 + ks * 32 + lk]);
        #pragma unroll
        for (int jt = 0; jt < 2; jt++)
            #pragma unroll
            for (int it = 0; it < 8; it++)
                acc[jt][it] = __builtin_amdgcn_mfma_f32_16x16x32_bf16(
                    b[it], a[jt][ks], acc[jt][it], 0, 0, 0);
    }

    #pragma unroll
    for (int jt = 0; jt < 2; jt++) {
        int row = r0 + jt * 16 + lr;
        if (row >= M) continue;
        #pragma unroll
        for (int it = 0; it < 8; it++) {
            float4 b4 = *reinterpret_cast<const float4*>(&bias[it * 16 + cq]);
            float4 o;
            o.x = acc[jt][it][0] + b4.x;
            o.y = acc[jt][it][1] + b4.y;
            o.z = acc[jt][it][2] + b4.z;
            o.w = acc[jt][it][3] + b4.w;
            *reinterpret_cast<float4*>(&O[(size_t)row * 128 + it * 16 + cq]) = o;
        }
    }
}

// ---------- launch ----------
extern "C" void kernel_launch(void* const* d_in, const int* in_sizes, int n_in,
                              void* d_out, int out_size, void* d_ws, size_t ws_size,
                              hipStream_t stream)
{
    const float* feats = (const float*)d_in[0];
    const int*   ei    = (const int*)d_in[1];
    const float* Wq = (const float*)d_in[3];
    const float* bq = (const float*)d_in[4];
    const float* Wk = (const float*)d_in[5];
    const float* bk = (const float*)d_in[6];
    const float* Wv = (const float*)d_in[7];
    const float* bv = (const float*)d_in[8];
    const float* Wo = (const float*)d_in[9];
    const float* bo = (const float*)d_in[10];
    float* out = (float*)d_out;

    const int N = in_sizes[0] / 128;
    const int E = in_sizes[1] / 2;
    const int nb = (N + 1023) / 1024;
    const int ntiles = (N + (1 << TILE_SHIFT) - 1) >> TILE_SHIFT;

    char* ws = (char*)d_ws;
    size_t off = 0;
    auto alloc = [&](size_t bytes) -> void* {
        void* p = ws + off;
        off += (bytes + 255) & ~(size_t)255;
        return p;
    };
    unsigned short* qb   = (unsigned short*)alloc((size_t)N * 128 * 2);
    unsigned short* kb   = (unsigned short*)alloc((size_t)N * 128 * 2);
    unsigned short* vb   = (unsigned short*)alloc((size_t)N * 128 * 2);
    unsigned short* accb = (unsigned short*)alloc((size_t)N * 128 * 2);
    unsigned int* ebuf = (unsigned int*)accb;  // alias: ebuf lifetime disjoint from accb
    int* counts   = (int*)alloc(((size_t)N + 1 + MAXTILES) * 4);   // counts | bfill
    int* bfill    = counts + (N + 1);
    int* offsets  = (int*)alloc(((size_t)N + 1) * 4);
    int* sorted_r = (int*)alloc((size_t)E * 4);
    int* blkSum   = (int*)alloc(256 * 4);
    int* blkOff   = (int*)alloc(256 * 4);
    unsigned short* Wqb = (unsigned short*)alloc(128 * 128 * 2);
    unsigned short* Wkb = (unsigned short*)alloc(128 * 128 * 2);
    unsigned short* Wvb = (unsigned short*)alloc(128 * 128 * 2);
    unsigned short* Wob = (unsigned short*)alloc(128 * 128 * 2);

    hipMemsetAsync(counts, 0, ((size_t)N + 1 + MAXTILES) * 4, stream);

    wconv_hist<<<64 + (E + 255) / 256, 256, 0, stream>>>(
        Wq, Wk, Wv, Wo, Wqb, Wkb, Wvb, Wob, ei, counts, E);

    scan1_kernel<<<nb, 1024, 0, stream>>>(counts, offsets, blkSum, N);
    scan2_kernel<<<1, 64, 0, stream>>>(blkSum, blkOff, offsets, nb, N);
    scan3_kernel<<<nb, 1024, 0, stream>>>(offsets, blkOff, N);

    const int gx  = (N + 127) / 128;
    const int nsb = (E + 4095) / 4096;
    qkv_bin<<<gx + nsb, 256, 0, stream>>>(feats, Wqb, bq, Wkb, bk, Wvb, bv,
                                          qb, kb, vb, N, gx,
                                          ei, offsets, bfill, ebuf, E, nsb);

    tile_sort<<<ntiles, 256, 0, stream>>>(ebuf, offsets, sorted_r, N);

    edge_attn_kernel<<<(N + 3) / 4, 256, 0, stream>>>(qb, kb, vb, offsets, sorted_r, accb, N);

    out_gemm<<<gx, 256, 0, stream>>>(accb, Wob, bo, out, N);
}

// Round 11
// 306.986 us; speedup vs baseline: 1.1058x; 1.0158x over previous
//
#include <hip/hip_runtime.h>
#include <hip/hip_bf16.h>

typedef __attribute__((ext_vector_type(8))) short bh8;
typedef __attribute__((ext_vector_type(4))) float f32x4;

__device__ __forceinline__ float bfbits2f(unsigned short s) {
    union { unsigned int u; float f; } cv;
    cv.u = ((unsigned int)s) << 16;
    return cv.f;
}
__device__ __forceinline__ unsigned short f2bfbits(float f) {
    union { float f; unsigned int u; } cv; cv.f = f;
    unsigned int u = cv.u;
    u += 0x7fffu + ((u >> 16) & 1u);   // round-to-nearest-even
    return (unsigned short)(u >> 16);
}
__device__ __forceinline__ unsigned int pack2bf(float a, float b) {
    return (unsigned int)f2bfbits(a) | (((unsigned int)f2bfbits(b)) << 16);
}

// ---------- fused prep: W conv | feats conv | histogram-with-rank ----------
// blocks [0,64): W fp32->bf16 (4 matrices).
// blocks [64, 64+nfc): feats fp32->bf16 (8 elems/thread).
// blocks [64+nfc, ...): edge histogram + rank tickets.
__global__ __launch_bounds__(256)
void prep_kernel(const float* __restrict__ w0, const float* __restrict__ w1,
                 const float* __restrict__ w2, const float* __restrict__ w3,
                 unsigned short* __restrict__ o0, unsigned short* __restrict__ o1,
                 unsigned short* __restrict__ o2, unsigned short* __restrict__ o3,
                 const float* __restrict__ feats, unsigned short* __restrict__ fb,
                 int totElems, int nfc,
                 const int* __restrict__ ei, int* __restrict__ counts,
                 int* __restrict__ rank, int E)
{
    if (blockIdx.x < 64) {
        const float* src[4] = {w0, w1, w2, w3};
        unsigned short* dst[4] = {o0, o1, o2, o3};
        const float* s = src[blockIdx.x >> 4];
        unsigned short* d = dst[blockIdx.x >> 4];
        int i = ((blockIdx.x & 15) * 256 + threadIdx.x) * 4;
        float4 f = *reinterpret_cast<const float4*>(&s[i]);
        uint2 p;
        p.x = pack2bf(f.x, f.y);
        p.y = pack2bf(f.z, f.w);
        *reinterpret_cast<uint2*>(&d[i]) = p;
        return;
    }
    if (blockIdx.x < (unsigned)(64 + nfc)) {
        int i = ((blockIdx.x - 64) * 256 + threadIdx.x) * 8;
        if (i + 8 <= totElems) {
            float4 f0 = *reinterpret_cast<const float4*>(&feats[i]);
            float4 f1 = *reinterpret_cast<const float4*>(&feats[i + 4]);
            uint4 p;
            p.x = pack2bf(f0.x, f0.y);
            p.y = pack2bf(f0.z, f0.w);
            p.z = pack2bf(f1.x, f1.y);
            p.w = pack2bf(f1.z, f1.w);
            *reinterpret_cast<uint4*>(&fb[i]) = p;
        } else {
            for (int j = i; j < totElems; j++) fb[j] = f2bfbits(feats[j]);
        }
        return;
    }
    int e = (blockIdx.x - 64 - nfc) * 256 + threadIdx.x;
    if (e < E) {
        int2 rc = reinterpret_cast<const int2*>(ei)[e];
        rank[e] = atomicAdd(&counts[rc.y], 1);
    }
}

// ---------- scans ----------
__device__ __forceinline__ int wave_incl_scan(int v, int lane) {
    #pragma unroll
    for (int off = 1; off < 64; off <<= 1) {
        int y = __shfl_up(v, off);
        if (lane >= off) v += y;
    }
    return v;
}

__global__ __launch_bounds__(1024)
void scan1_kernel(const int* __restrict__ counts, int* __restrict__ offs,
                  int* __restrict__ blkSum, int n)
{
    __shared__ int wsum[16];
    __shared__ int woff[16];
    const int t = threadIdx.x, lane = t & 63, w = t >> 6;
    int i = blockIdx.x * 1024 + t;
    int x = (i < n) ? counts[i] : 0;
    int v = wave_incl_scan(x, lane);
    if (lane == 63) wsum[w] = v;
    __syncthreads();
    if (t == 0) {
        int s = 0;
        #pragma unroll
        for (int j = 0; j < 16; j++) { int tmp = wsum[j]; woff[j] = s; s += tmp; }
        blkSum[blockIdx.x] = s;
    }
    __syncthreads();
    if (i < n) offs[i] = woff[w] + v - x;
}

__global__ void scan2_kernel(const int* __restrict__ blkSum, int* __restrict__ blkOff,
                             int* __restrict__ offs, int nb, int n)
{
    const int lane = threadIdx.x;   // 64 threads
    int carry = 0;
    for (int base = 0; base < nb; base += 64) {
        int x = (base + lane < nb) ? blkSum[base + lane] : 0;
        int v = wave_incl_scan(x, lane);
        if (base + lane < nb) blkOff[base + lane] = carry + v - x;
        carry += __shfl(v, 63);
    }
    if (lane == 0) offs[n] = carry;
}

__global__ __launch_bounds__(1024)
void scan3_kernel(int* __restrict__ offs, const int* __restrict__ blkOff, int n)
{
    int i = blockIdx.x * 1024 + threadIdx.x;
    if (i < n) offs[i] += blkOff[blockIdx.x];
}

// ---------- fused QKV GEMM (bf16 A) + atomic-free scatter (blockIdx split) ----------
__global__ __launch_bounds__(256)
void qkv_scatter(const unsigned short* __restrict__ Af,
                 const unsigned short* __restrict__ Wqb, const float* __restrict__ bq,
                 const unsigned short* __restrict__ Wkb, const float* __restrict__ bk,
                 const unsigned short* __restrict__ Wvb, const float* __restrict__ bv,
                 unsigned short* __restrict__ Oq, unsigned short* __restrict__ Ok,
                 unsigned short* __restrict__ Ov, int M, int gx,
                 const int* __restrict__ ei, const int* __restrict__ offsets,
                 const int* __restrict__ rank, int* __restrict__ sorted_r,
                 int E, int nsb)
{
    if (blockIdx.x >= (unsigned)gx) {
        int sb = blockIdx.x - gx;
        int stride = nsb * 256;
        for (int e = sb * 256 + threadIdx.x; e < E; e += stride) {
            int2 rc = reinterpret_cast<const int2*>(ei)[e];
            sorted_r[offsets[rc.y] + rank[e]] = rc.x;
        }
        return;
    }

    const int lane = threadIdx.x & 63;
    const int w    = threadIdx.x >> 6;
    const int r0   = blockIdx.x * 128 + w * 32;
    const int lr   = lane & 15;
    const int lk   = (lane >> 4) * 8;
    const int cq   = (lane >> 4) * 4;

    bh8 a[2][4];
    #pragma unroll
    for (int jt = 0; jt < 2; jt++) {
        int row = r0 + jt * 16 + lr; if (row >= M) row = M - 1;
        const unsigned short* ap = &Af[(size_t)row * 128 + lk];
        #pragma unroll
        for (int ks = 0; ks < 4; ks++)
            a[jt][ks] = *reinterpret_cast<const bh8*>(ap + ks * 32);
    }

    const unsigned short* Ws[3] = {Wqb, Wkb, Wvb};
    const float* Bs[3] = {bq, bk, bv};
    unsigned short* Os[3] = {Oq, Ok, Ov};

    #pragma unroll
    for (int wsel = 0; wsel < 3; wsel++) {
        const unsigned short* W = Ws[wsel];
        f32x4 acc[2][8];
        #pragma unroll
        for (int jt = 0; jt < 2; jt++)
            #pragma unroll
            for (int it = 0; it < 8; it++)
                #pragma unroll
                for (int q = 0; q < 4; q++) acc[jt][it][q] = 0.f;

        #pragma unroll
        for (int ks = 0; ks < 4; ks++) {
            bh8 b[8];
            #pragma unroll
            for (int it = 0; it < 8; it++)
                b[it] = *reinterpret_cast<const bh8*>(
                    &W[(size_t)(it * 16 + lr) * 128 + ks * 32 + lk]);
            #pragma unroll
            for (int jt = 0; jt < 2; jt++)
                #pragma unroll
                for (int it = 0; it < 8; it++)
                    acc[jt][it] = __builtin_amdgcn_mfma_f32_16x16x32_bf16(
                        b[it], a[jt][ks], acc[jt][it], 0, 0, 0);
        }

        const float* bias = Bs[wsel];
        unsigned short* O = Os[wsel];
        #pragma unroll
        for (int jt = 0; jt < 2; jt++) {
            int row = r0 + jt * 16 + lr;
            if (row >= M) continue;
            #pragma unroll
            for (int it = 0; it < 8; it++) {
                float4 b4 = *reinterpret_cast<const float4*>(&bias[it * 16 + cq]);
                uint2 pk;
                pk.x = pack2bf(acc[jt][it][0] + b4.x, acc[jt][it][1] + b4.y);
                pk.y = pack2bf(acc[jt][it][2] + b4.z, acc[jt][it][3] + b4.w);
                *reinterpret_cast<uint2*>(&O[(size_t)row * 128 + it * 16 + cq]) = pk;
            }
        }
    }
}

// ---------- edge attention: one wave per destination node, pipelined ----------
__global__ __launch_bounds__(256)
void edge_attn_kernel(const unsigned short* __restrict__ qb,
                      const unsigned short* __restrict__ kb,
                      const unsigned short* __restrict__ vb,
                      const int* __restrict__ offsets,
                      const int* __restrict__ sorted_r,
                      unsigned short* __restrict__ acc_out, int n)
{
    const int lane = threadIdx.x & 63;
    const int wid  = threadIdx.x >> 6;
    const int node = blockIdx.x * 4 + wid;
    if (node >= n) return;

    const int h    = lane & 7;    // head (score phase)
    const int eloc = lane >> 3;   // k-edge slot == head of owned dims (2*lane)
    const int seg0 = __builtin_amdgcn_readfirstlane(offsets[node]);
    const int segL = __builtin_amdgcn_readfirstlane(offsets[node + 1]) - seg0;
    const int nch  = (segL + 7) >> 3;
    const int* __restrict__ sr = sorted_r + seg0;

    float qf[16];
    {
        const uint4* p = reinterpret_cast<const uint4*>(&qb[(size_t)node * 128 + h * 16]);
        uint4 u0 = p[0], u1 = p[1];
        unsigned int uu[8] = {u0.x, u0.y, u0.z, u0.w, u1.x, u1.y, u1.z, u1.w};
        #pragma unroll
        for (int i = 0; i < 8; i++) {
            qf[2 * i]     = bfbits2f((unsigned short)(uu[i] & 0xffffu));
            qf[2 * i + 1] = bfbits2f((unsigned short)(uu[i] >> 16));
        }
    }

    float acc0 = 0.f, acc1 = 0.f, ssum = 0.f;

    uint4 kA0, kA1, kB0, kB1;
    unsigned int vA[8], vB[8];

    if (nch > 0) {
        int idx = (eloc < segL) ? eloc : (segL - 1);
        int rk  = sr[idx];
        const uint4* kp = reinterpret_cast<const uint4*>(&kb[(size_t)rk * 128 + h * 16]);
        kA0 = kp[0]; kA1 = kp[1];
        int ec0 = (segL < 8) ? segL : 8;
        #pragma unroll
        for (int e = 0; e < 8; e++) {
            int re = sr[(e < ec0) ? e : (ec0 - 1)];   // uniform -> s_load
            vA[e] = *reinterpret_cast<const unsigned int*>(&vb[(size_t)re * 128 + 2 * lane]);
        }
    }

    auto step = [&](int c, const uint4& ck0, const uint4& ck1, const unsigned int (&cv)[8],
                    uint4& nk0, uint4& nk1, unsigned int (&nv)[8]) {
        const int base = c << 3;
        if (c + 1 < nch) {
            int nb   = base + 8;
            int nidx = nb + eloc;
            int rk   = sr[(nidx < segL) ? nidx : (segL - 1)];
            const uint4* kp = reinterpret_cast<const uint4*>(&kb[(size_t)rk * 128 + h * 16]);
            nk0 = kp[0]; nk1 = kp[1];
            int ecn = segL - nb; if (ecn > 8) ecn = 8;
            #pragma unroll
            for (int e = 0; e < 8; e++) {
                int re = sr[nb + ((e < ecn) ? e : (ecn - 1))];
                nv[e] = *reinterpret_cast<const unsigned int*>(&vb[(size_t)re * 128 + 2 * lane]);
            }
        }
        unsigned int uu[8] = {ck0.x, ck0.y, ck0.z, ck0.w, ck1.x, ck1.y, ck1.z, ck1.w};
        float s = 0.f;
        #pragma unroll
        for (int i = 0; i < 8; i++) {
            s += qf[2 * i]     * bfbits2f((unsigned short)(uu[i] & 0xffffu));
            s += qf[2 * i + 1] * bfbits2f((unsigned short)(uu[i] >> 16));
        }
        float ex = (base + eloc < segL) ? __expf(s * 0.25f) : 0.f;
        ssum += ex;
        #pragma unroll
        for (int e = 0; e < 8; e++) {
            float exv = __shfl(ex, e * 8 + eloc);
            acc0 += exv * bfbits2f((unsigned short)(cv[e] & 0xffffu));
            acc1 += exv * bfbits2f((unsigned short)(cv[e] >> 16));
        }
    };

    int c = 0;
    while (c < nch) {
        step(c, kA0, kA1, vA, kB0, kB1, vB); c++;
        if (c >= nch) break;
        step(c, kB0, kB1, vB, kA0, kA1, vA); c++;
    }

    ssum += __shfl_xor(ssum, 8);
    ssum += __shfl_xor(ssum, 16);
    ssum += __shfl_xor(ssum, 32);
    float den = __shfl(ssum, lane >> 3) + 1e-16f;
    float rd  = 1.0f / den;

    reinterpret_cast<unsigned int*>(acc_out)[(size_t)node * 64 + lane] =
        pack2bf(acc0 * rd, acc1 * rd);
}

// ---------- output GEMM: out[M,128] = accb(bf16) @ Wo.T + bo, fp32 out ----------
__global__ __launch_bounds__(256)
void out_gemm(const unsigned short* __restrict__ A, const unsigned short* __restrict__ Wb,
              const float* __restrict__ bias, float* __restrict__ O, int M)
{
    const int lane = threadIdx.x & 63;
    const int w    = threadIdx.x >> 6;
    const int r0   = blockIdx.x * 128 + w * 32;
    const int lr   = lane & 15;
    const int lk   = (lane >> 4) * 8;
    const int cq   = (lane >> 4) * 4;

    bh8 a[2][4];
    #pragma unroll
    for (int jt = 0; jt < 2; jt++) {
        int row = r0 + jt * 16 + lr; if (row >= M) row = M - 1;
        const unsigned short* ap = &A[(size_t)row * 128 + lk];
        #pragma unroll
        for (int ks = 0; ks < 4; ks++)
            a[jt][ks] = *reinterpret_cast<const bh8*>(ap + ks * 32);
    }

    f32x4 acc[2][8];
    #pragma unroll
    for (int jt = 0; jt < 2; jt++)
        #pragma unroll
        for (int it = 0; it < 8; it++)
            #pragma unroll
            for (int q = 0; q < 4; q++) acc[jt][it][q] = 0.f;

    #pragma unroll
    for (int ks = 0; ks < 4; ks++) {
        bh8 b[8];
        #pragma unroll
        for (int it = 0; it < 8; it++)
            b[it] = *reinterpret_cast<const bh8*>(
                &Wb[(size_t)(it * 16 + lr) * 128 + ks * 32 + lk]);
        #pragma unroll
        for (int jt = 0; jt < 2; jt++)
            #pragma unroll
            for (int it = 0; it < 8; it++)
                acc[jt][it] = __builtin_amdgcn_mfma_f32_16x16x32_bf16(
                    b[it], a[jt][ks], acc[jt][it], 0, 0, 0);
    }

    #pragma unroll
    for (int jt = 0; jt < 2; jt++) {
        int row = r0 + jt * 16 + lr;
        if (row >= M) continue;
        #pragma unroll
        for (int it = 0; it < 8; it++) {
            float4 b4 = *reinterpret_cast<const float4*>(&bias[it * 16 + cq]);
            float4 o;
            o.x = acc[jt][it][0] + b4.x;
            o.y = acc[jt][it][1] + b4.y;
            o.z = acc[jt][it][2] + b4.z;
            o.w = acc[jt][it][3] + b4.w;
            *reinterpret_cast<float4*>(&O[(size_t)row * 128 + it * 16 + cq]) = o;
        }
    }
}

// ---------- launch ----------
extern "C" void kernel_launch(void* const* d_in, const int* in_sizes, int n_in,
                              void* d_out, int out_size, void* d_ws, size_t ws_size,
                              hipStream_t stream)
{
    const float* feats = (const float*)d_in[0];
    const int*   ei    = (const int*)d_in[1];
    const float* Wq = (const float*)d_in[3];
    const float* bq = (const float*)d_in[4];
    const float* Wk = (const float*)d_in[5];
    const float* bk = (const float*)d_in[6];
    const float* Wv = (const float*)d_in[7];
    const float* bv = (const float*)d_in[8];
    const float* Wo = (const float*)d_in[9];
    const float* bo = (const float*)d_in[10];
    float* out = (float*)d_out;

    const int N = in_sizes[0] / 128;
    const int E = in_sizes[1] / 2;
    const int nb = (N + 1023) / 1024;
    const int totElems = N * 128;
    const int nfc = (totElems + 2047) / 2048;
    const int nhb = (E + 255) / 256;

    char* ws = (char*)d_ws;
    size_t off = 0;
    auto alloc = [&](size_t bytes) -> void* {
        void* p = ws + off;
        off += (bytes + 255) & ~(size_t)255;
        return p;
    };
    unsigned short* qb   = (unsigned short*)alloc((size_t)N * 128 * 2);
    unsigned short* kb   = (unsigned short*)alloc((size_t)N * 128 * 2);
    unsigned short* vb   = (unsigned short*)alloc((size_t)N * 128 * 2);
    unsigned short* accb = (unsigned short*)alloc((size_t)N * 128 * 2);
    int* rank     = (int*)accb;   // alias: rank lifetime (hist->scatter) disjoint from accb
    unsigned short* fb = (unsigned short*)alloc((size_t)N * 128 * 2);  // feats bf16
    int* counts   = (int*)alloc(((size_t)N + 1) * 4);
    int* offsets  = (int*)alloc(((size_t)N + 1) * 4);
    int* sorted_r = (int*)alloc((size_t)E * 4);
    int* blkSum   = (int*)alloc(256 * 4);
    int* blkOff   = (int*)alloc(256 * 4);
    unsigned short* Wqb = (unsigned short*)alloc(128 * 128 * 2);
    unsigned short* Wkb = (unsigned short*)alloc(128 * 128 * 2);
    unsigned short* Wvb = (unsigned short*)alloc(128 * 128 * 2);
    unsigned short* Wob = (unsigned short*)alloc(128 * 128 * 2);

    hipMemsetAsync(counts, 0, ((size_t)N + 1) * 4, stream);

    prep_kernel<<<64 + nfc + nhb, 256, 0, stream>>>(
        Wq, Wk, Wv, Wo, Wqb, Wkb, Wvb, Wob,
        feats, fb, totElems, nfc, ei, counts, rank, E);

    scan1_kernel<<<nb, 1024, 0, stream>>>(counts, offsets, blkSum, N);
    scan2_kernel<<<1, 64, 0, stream>>>(blkSum, blkOff, offsets, nb, N);
    scan3_kernel<<<nb, 1024, 0, stream>>>(offsets, blkOff, N);

    const int gx  = (N + 127) / 128;
    const int nsb = 1024;
    qkv_scatter<<<gx + nsb, 256, 0, stream>>>(fb, Wqb, bq, Wkb, bk, Wvb, bv,
                                              qb, kb, vb, N, gx,
                                              ei, offsets, rank, sorted_r, E, nsb);

    edge_attn_kernel<<<(N + 3) / 4, 256, 0, stream>>>(qb, kb, vb, offsets, sorted_r, accb, N);

    out_gemm<<<gx, 256, 0, stream>>>(accb, Wob, bo, out, N);
}